// Round 1
// baseline (4691.620 us; speedup 1.0000x reference)
//
#include <hip/hip_runtime.h>
#include <math.h>

#define NG   65536
#define MTOK 512
#define DIM  512
#define SCALE_ATT 0.125f
#define LN_EPS 1e-5f

// ---------------------------------------------------------------------------
// 4x4 outer-product FMA helper
// ---------------------------------------------------------------------------
__device__ __forceinline__ void fma44(float (&acc)[4][4], const float4& a, const float4& b) {
    acc[0][0] += a.x*b.x; acc[0][1] += a.x*b.y; acc[0][2] += a.x*b.z; acc[0][3] += a.x*b.w;
    acc[1][0] += a.y*b.x; acc[1][1] += a.y*b.y; acc[1][2] += a.y*b.z; acc[1][3] += a.y*b.w;
    acc[2][0] += a.z*b.x; acc[2][1] += a.z*b.y; acc[2][2] += a.z*b.z; acc[2][3] += a.z*b.w;
    acc[3][0] += a.w*b.x; acc[3][1] += a.w*b.y; acc[3][2] += a.w*b.z; acc[3][3] += a.w*b.w;
}

// ---------------------------------------------------------------------------
// C[i,j] = sum_k A[i,k]*B[j,k] (+ A2[i,k]*B2[j,k]) (+bias1[j]+bias2[j]) (+addend[i,j])
// 128x128 tile, 256 threads, 8x8 microtile as four 4x4 quadrants, k-step 8.
// Requires Mrows,Ncols multiples of 128 and K multiple of 8.
// ---------------------------------------------------------------------------
__global__ __launch_bounds__(256)
void gemm_bt128(const float* __restrict__ A,  const float* __restrict__ B,
                const float* __restrict__ A2, const float* __restrict__ B2,
                const float* __restrict__ bias1, const float* __restrict__ bias2,
                const float* __restrict__ addend,
                float* __restrict__ C,
                int K, int lda, int ldb, long ldc)
{
    __shared__ __align__(16) float As[8][132];
    __shared__ __align__(16) float Bs[8][132];
    const int tid = threadIdx.x;
    const int tx = tid & 15;         // j quad index
    const int ty = tid >> 4;         // i quad index
    const long i0 = (long)blockIdx.y * 128;
    const long j0 = (long)blockIdx.x * 128;
    const int lr = tid >> 1;         // 0..127 tile row for staging
    const int lk = (tid & 1) * 4;    // 0 or 4

    float acc[2][2][4][4] = {};

    for (int pair = 0; pair < 2; ++pair) {
        const float* Ap = pair ? A2 : A;
        const float* Bp = pair ? B2 : B;
        if (Ap == nullptr) break;
        for (int k0 = 0; k0 < K; k0 += 8) {
            float4 av = *(const float4*)&Ap[(i0 + lr) * (long)lda + k0 + lk];
            float4 bv = *(const float4*)&Bp[(j0 + lr) * (long)ldb + k0 + lk];
            __syncthreads();
            As[lk+0][lr] = av.x; As[lk+1][lr] = av.y; As[lk+2][lr] = av.z; As[lk+3][lr] = av.w;
            Bs[lk+0][lr] = bv.x; Bs[lk+1][lr] = bv.y; Bs[lk+2][lr] = bv.z; Bs[lk+3][lr] = bv.w;
            __syncthreads();
            #pragma unroll
            for (int kk = 0; kk < 8; ++kk) {
                float4 a0 = *(const float4*)&As[kk][ty*4];
                float4 a1 = *(const float4*)&As[kk][64 + ty*4];
                float4 b0 = *(const float4*)&Bs[kk][tx*4];
                float4 b1 = *(const float4*)&Bs[kk][64 + tx*4];
                fma44(acc[0][0], a0, b0); fma44(acc[0][1], a0, b1);
                fma44(acc[1][0], a1, b0); fma44(acc[1][1], a1, b1);
            }
        }
    }

    #pragma unroll
    for (int qi = 0; qi < 2; ++qi) {
        #pragma unroll
        for (int rr = 0; rr < 4; ++rr) {
            const long r = i0 + qi*64 + ty*4 + rr;
            #pragma unroll
            for (int qj = 0; qj < 2; ++qj) {
                const long c = j0 + qj*64 + tx*4;
                float4 v;
                v.x = acc[qi][qj][rr][0]; v.y = acc[qi][qj][rr][1];
                v.z = acc[qi][qj][rr][2]; v.w = acc[qi][qj][rr][3];
                if (bias1) { v.x += bias1[c]; v.y += bias1[c+1]; v.z += bias1[c+2]; v.w += bias1[c+3]; }
                if (bias2) { v.x += bias2[c]; v.y += bias2[c+1]; v.z += bias2[c+2]; v.w += bias2[c+3]; }
                if (addend) {
                    float4 ad = *(const float4*)&addend[r*ldc + c];
                    v.x += ad.x; v.y += ad.y; v.z += ad.z; v.w += ad.w;
                }
                *(float4*)&C[r*ldc + c] = v;
            }
        }
    }
}

// ---------------------------------------------------------------------------
// Split-K GEMM: Cpart[z][i,j] = sum_{k in chunk z} A[i,k]*B[k,j]
// A = pool [512, 65536] (lda=65536), B = g_p [65536, 512] (ldb=512)
// 128x128 tile, grid (4,4,S)
// ---------------------------------------------------------------------------
__global__ __launch_bounds__(256)
void gemm_ab128_splitk(const float* __restrict__ A, const float* __restrict__ B,
                       float* __restrict__ Cpart, int kchunk)
{
    __shared__ __align__(16) float As[8][132];
    __shared__ __align__(16) float Bs[8][132];
    const int tid = threadIdx.x;
    const int tx = tid & 15;
    const int ty = tid >> 4;
    const long i0 = (long)blockIdx.y * 128;
    const long j0 = (long)blockIdx.x * 128;
    const int kbase = blockIdx.z * kchunk;
    const int lr = tid >> 1;
    const int lk = (tid & 1) * 4;
    const int bkr = tid >> 5;        // 0..7  B k-row
    const int bc  = (tid & 31) * 4;  // 0..124

    float acc[2][2][4][4] = {};

    for (int k0 = kbase; k0 < kbase + kchunk; k0 += 8) {
        float4 av = *(const float4*)&A[(i0 + lr) * 65536L + k0 + lk];
        float4 bv = *(const float4*)&B[(long)(k0 + bkr) * 512 + j0 + bc];
        __syncthreads();
        As[lk+0][lr] = av.x; As[lk+1][lr] = av.y; As[lk+2][lr] = av.z; As[lk+3][lr] = av.w;
        *(float4*)&Bs[bkr][bc] = bv;
        __syncthreads();
        #pragma unroll
        for (int kk = 0; kk < 8; ++kk) {
            float4 a0 = *(const float4*)&As[kk][ty*4];
            float4 a1 = *(const float4*)&As[kk][64 + ty*4];
            float4 b0 = *(const float4*)&Bs[kk][tx*4];
            float4 b1 = *(const float4*)&Bs[kk][64 + tx*4];
            fma44(acc[0][0], a0, b0); fma44(acc[0][1], a0, b1);
            fma44(acc[1][0], a1, b0); fma44(acc[1][1], a1, b1);
        }
    }

    float* Cp = Cpart + (size_t)blockIdx.z * (512*512);
    #pragma unroll
    for (int qi = 0; qi < 2; ++qi) {
        #pragma unroll
        for (int rr = 0; rr < 4; ++rr) {
            const long r = i0 + qi*64 + ty*4 + rr;
            #pragma unroll
            for (int qj = 0; qj < 2; ++qj) {
                const long c = j0 + qj*64 + tx*4;
                float4 v;
                v.x = acc[qi][qj][rr][0]; v.y = acc[qi][qj][rr][1];
                v.z = acc[qi][qj][rr][2]; v.w = acc[qi][qj][rr][3];
                *(float4*)&Cp[r*512 + c] = v;
            }
        }
    }
}

__global__ __launch_bounds__(256)
void reduce_parts16(const float* __restrict__ part, float* __restrict__ outp)
{
    const size_t idx = ((size_t)blockIdx.x * 256 + threadIdx.x) * 4;
    float4 s = *(const float4*)&part[idx];
    #pragma unroll
    for (int p = 1; p < 16; ++p) {
        float4 v = *(const float4*)&part[(size_t)p * 262144 + idx];
        s.x += v.x; s.y += v.y; s.z += v.z; s.w += v.w;
    }
    *(float4*)&outp[idx] = s;
}

// ---------------------------------------------------------------------------
// In-place row softmax over 65536 columns; one block per row.
// ---------------------------------------------------------------------------
__global__ __launch_bounds__(256)
void softmax_rows(float* __restrict__ L)
{
    __shared__ float red[4];
    const long base = (long)blockIdx.x * 65536;
    const int tid = threadIdx.x;

    float mx = -3.0e38f;
    for (int i = tid*4; i < 65536; i += 1024) {
        float4 v = *(const float4*)&L[base + i];
        mx = fmaxf(mx, fmaxf(fmaxf(v.x, v.y), fmaxf(v.z, v.w)));
    }
    #pragma unroll
    for (int off = 32; off > 0; off >>= 1) mx = fmaxf(mx, __shfl_xor(mx, off, 64));
    if ((tid & 63) == 0) red[tid >> 6] = mx;
    __syncthreads();
    mx = fmaxf(fmaxf(red[0], red[1]), fmaxf(red[2], red[3]));
    __syncthreads();

    float s = 0.f;
    for (int i = tid*4; i < 65536; i += 1024) {
        float4 v = *(const float4*)&L[base + i];
        v.x = __expf(v.x - mx); v.y = __expf(v.y - mx);
        v.z = __expf(v.z - mx); v.w = __expf(v.w - mx);
        *(float4*)&L[base + i] = v;
        s += v.x + v.y + v.z + v.w;
    }
    #pragma unroll
    for (int off = 32; off > 0; off >>= 1) s += __shfl_xor(s, off, 64);
    if ((tid & 63) == 0) red[tid >> 6] = s;
    __syncthreads();
    s = red[0] + red[1] + red[2] + red[3];
    const float inv = 1.f / s;

    for (int i = tid*4; i < 65536; i += 1024) {
        float4 v = *(const float4*)&L[base + i];
        v.x *= inv; v.y *= inv; v.z *= inv; v.w *= inv;
        *(float4*)&L[base + i] = v;
    }
}

// ---------------------------------------------------------------------------
// Fused: S = Q Kt * SCALE -> softmax over M -> O = P V + g -> LayerNorm -> out
// 16 Q-rows per block, 256 threads (ti=row 0..15, tj=col-quad 0..15).
// LDS: Ss[16][520] scores, Kt[64][68] (K staged TRANSPOSED in phase1 to kill
// 8-way bank conflicts; V staged natural in phase3), Qt[16][68]. Total 55 KB.
// O accumulator lives in registers (32 floats/thread).
// ---------------------------------------------------------------------------
__global__ __launch_bounds__(256)
void attn_ln(const float* __restrict__ Q, const float* __restrict__ Km,
             const float* __restrict__ Vm, const float* __restrict__ g,
             const float* __restrict__ gamma, const float* __restrict__ beta,
             float* __restrict__ out)
{
    __shared__ __align__(16) float Ss[16*520];
    __shared__ __align__(16) float Kt[64*68];
    __shared__ __align__(16) float Qt[16*68];
    const int tid = threadIdx.x;
    const long n0 = (long)blockIdx.x * 16;
    const int ti = tid >> 4;   // Q row 0..15
    const int tj = tid & 15;   // quad 0..15

    // zero the score accumulator
    #pragma unroll
    for (int rep = 0; rep < 8; ++rep) {
        int flat = rep*1024 + tid*4;
        int i = flat >> 9, d = flat & 511;
        *(float4*)&Ss[i*520 + d] = make_float4(0.f, 0.f, 0.f, 0.f);
    }

    // ---- phase 1: S += Q(:,dt-chunk) . K(:,dt-chunk)^T ----
    for (int dt = 0; dt < 8; ++dt) {
        __syncthreads();
        {   // stage Q subtile [16][64]
            int qi = tid >> 4, qc = (tid & 15) << 2;
            *(float4*)&Qt[qi*68 + qc] = *(const float4*)&Q[(n0 + qi)*DIM + dt*64 + qc];
        }
        for (int mt = 0; mt < 8; ++mt) {
            __syncthreads();
            #pragma unroll
            for (int rep = 0; rep < 4; ++rep) {   // stage K subtile transposed: Kt[d][m]
                int flat = rep*1024 + tid*4;
                int mr = flat >> 6, dc = flat & 63;
                float4 kv = *(const float4*)&Km[(long)(mt*64 + mr)*DIM + dt*64 + dc];
                Kt[(dc+0)*68 + mr] = kv.x;
                Kt[(dc+1)*68 + mr] = kv.y;
                Kt[(dc+2)*68 + mr] = kv.z;
                Kt[(dc+3)*68 + mr] = kv.w;
            }
            __syncthreads();
            float a0 = 0.f, a1 = 0.f, a2 = 0.f, a3 = 0.f;
            #pragma unroll 16
            for (int dd = 0; dd < 64; ++dd) {
                float   qv = Qt[ti*68 + dd];
                float4  kv = *(const float4*)&Kt[dd*68 + (tj<<2)];
                a0 += qv*kv.x; a1 += qv*kv.y; a2 += qv*kv.z; a3 += qv*kv.w;
            }
            float* sp = &Ss[ti*520 + mt*64 + (tj<<2)];
            float4 o = *(float4*)sp;
            o.x += a0; o.y += a1; o.z += a2; o.w += a3;
            *(float4*)sp = o;
        }
    }
    __syncthreads();

    // ---- phase 2: softmax over M=512 per row (one wave handles 4 rows) ----
    {
        const int wid = tid >> 6;
        const int lane = tid & 63;
        #pragma unroll
        for (int r4 = 0; r4 < 4; ++r4) {
            const int row = wid*4 + r4;
            float v[8];
            float mx = -3.0e38f;
            #pragma unroll
            for (int j = 0; j < 8; ++j) {
                v[j] = Ss[row*520 + j*64 + lane] * SCALE_ATT;
                mx = fmaxf(mx, v[j]);
            }
            #pragma unroll
            for (int off = 32; off > 0; off >>= 1) mx = fmaxf(mx, __shfl_xor(mx, off, 64));
            float s = 0.f;
            #pragma unroll
            for (int j = 0; j < 8; ++j) { v[j] = __expf(v[j] - mx); s += v[j]; }
            #pragma unroll
            for (int off = 32; off > 0; off >>= 1) s += __shfl_xor(s, off, 64);
            const float inv = 1.f / s;
            #pragma unroll
            for (int j = 0; j < 8; ++j) Ss[row*520 + j*64 + lane] = v[j] * inv;
        }
    }
    __syncthreads();

    // ---- phase 3: O = P V, O kept in registers oacc[8][4] ----
    float oacc[8][4] = {};
    #pragma unroll
    for (int dt = 0; dt < 8; ++dt) {
        for (int mt = 0; mt < 8; ++mt) {
            __syncthreads();
            #pragma unroll
            for (int rep = 0; rep < 4; ++rep) {   // stage V subtile natural: Kt[m][d]
                int flat = rep*1024 + tid*4;
                int mr = flat >> 6, dc = flat & 63;
                *(float4*)&Kt[mr*68 + dc] =
                    *(const float4*)&Vm[(long)(mt*64 + mr)*DIM + dt*64 + dc];
            }
            __syncthreads();
            #pragma unroll 16
            for (int m2 = 0; m2 < 64; ++m2) {
                float  p  = Ss[ti*520 + mt*64 + m2];
                float4 vv = *(const float4*)&Kt[m2*68 + (tj<<2)];
                oacc[dt][0] += p*vv.x; oacc[dt][1] += p*vv.y;
                oacc[dt][2] += p*vv.z; oacc[dt][3] += p*vv.w;
            }
        }
    }

    // ---- phase 4: += g, LayerNorm over DIM (row spread over 16 lanes) ----
    float sum = 0.f;
    #pragma unroll
    for (int dt = 0; dt < 8; ++dt) {
        float4 gv = *(const float4*)&g[(n0 + ti)*DIM + dt*64 + (tj<<2)];
        oacc[dt][0] += gv.x; oacc[dt][1] += gv.y;
        oacc[dt][2] += gv.z; oacc[dt][3] += gv.w;
        sum += oacc[dt][0] + oacc[dt][1] + oacc[dt][2] + oacc[dt][3];
    }
    #pragma unroll
    for (int off = 1; off < 16; off <<= 1) sum += __shfl_xor(sum, off, 64);
    const float mu = sum * (1.f/512.f);
    float qs = 0.f;
    #pragma unroll
    for (int dt = 0; dt < 8; ++dt) {
        #pragma unroll
        for (int c = 0; c < 4; ++c) { float dv = oacc[dt][c] - mu; qs += dv*dv; }
    }
    #pragma unroll
    for (int off = 1; off < 16; off <<= 1) qs += __shfl_xor(qs, off, 64);
    const float rstd = rsqrtf(qs * (1.f/512.f) + LN_EPS);
    #pragma unroll
    for (int dt = 0; dt < 8; ++dt) {
        const int dbase = dt*64 + (tj<<2);
        float4 gm = *(const float4*)&gamma[dbase];
        float4 bt = *(const float4*)&beta[dbase];
        float4 o;
        o.x = (oacc[dt][0] - mu)*rstd*gm.x + bt.x;
        o.y = (oacc[dt][1] - mu)*rstd*gm.y + bt.y;
        o.z = (oacc[dt][2] - mu)*rstd*gm.z + bt.z;
        o.w = (oacc[dt][3] - mu)*rstd*gm.w + bt.w;
        *(float4*)&out[(n0 + ti)*DIM + dbase] = o;
    }
}

// ---------------------------------------------------------------------------
extern "C" void kernel_launch(void* const* d_in, const int* in_sizes, int n_in,
                              void* d_out, int out_size, void* d_ws, size_t ws_size,
                              hipStream_t stream)
{
    (void)in_sizes; (void)n_in; (void)out_size; (void)ws_size;
    const float* g    = (const float*)d_in[0];
    const float* g_p  = (const float*)d_in[1];
    const float* W    = (const float*)d_in[2];   // [1, 512, 512] == Ws
    const float* Wq   = (const float*)d_in[3];
    const float* bq   = (const float*)d_in[4];
    const float* Wk   = (const float*)d_in[5];
    const float* bk   = (const float*)d_in[6];
    const float* Wv   = (const float*)d_in[7];
    const float* bv   = (const float*)d_in[8];
    const float* Wgp  = (const float*)d_in[9];
    const float* bgp  = (const float*)d_in[10];
    const float* Wkp  = (const float*)d_in[11];
    const float* bkp  = (const float*)d_in[12];
    const float* gamma= (const float*)d_in[13];
    const float* beta = (const float*)d_in[14];
    float* out = (float*)d_out;

    // workspace: 16 split-K partials (16 MB) + k_p0 + k_p + K + V  (= 20 MB)
    float* w    = (float*)d_ws;
    float* part = w;
    float* kp0  = w + (size_t)16*262144;
    float* kp   = kp0 + 262144;
    float* Kmat = kp  + 262144;
    float* Vmat = Kmat + 262144;

    // 1) L = Ws @ g^T  -> d_out viewed as [512, 65536]
    gemm_bt128<<<dim3(512, 4), 256, 0, stream>>>(
        W, g, nullptr, nullptr, nullptr, nullptr, nullptr,
        out, 512, 512, 512, (long)65536);

    // 2) pool = softmax(L) rows, in place
    softmax_rows<<<dim3(512), 256, 0, stream>>>(out);

    // 3) k_p0 = pool @ g_p  (split-K 16)
    gemm_ab128_splitk<<<dim3(4, 4, 16), 256, 0, stream>>>(out, g_p, part, 4096);
    reduce_parts16<<<dim3(256), 256, 0, stream>>>(part, kp0);

    // 4) small GEMMs: k_p, K, V
    gemm_bt128<<<dim3(4, 4), 256, 0, stream>>>(
        kp0, Wkp, nullptr, nullptr, bkp, nullptr, nullptr, kp, 512, 512, 512, (long)512);
    gemm_bt128<<<dim3(4, 4), 256, 0, stream>>>(
        W, Wk, nullptr, nullptr, bk, nullptr, kp, Kmat, 512, 512, 512, (long)512);
    gemm_bt128<<<dim3(4, 4), 256, 0, stream>>>(
        W, Wv, nullptr, nullptr, bv, nullptr, nullptr, Vmat, 512, 512, 512, (long)512);

    // 5) Q = g @ Wq^T + g_p @ Wgp^T + bq + bgp  -> d_out as [65536, 512]
    gemm_bt128<<<dim3(4, 512), 256, 0, stream>>>(
        g, Wq, g_p, Wgp, bq, bgp, nullptr, out, 512, 512, 512, (long)512);

    // 6) fused attention + residual + LayerNorm -> d_out (in place per 16-row block)
    attn_ln<<<dim3(4096), 256, 0, stream>>>(out, Kmat, Vmat, g, gamma, beta, out);
}